// Round 3
// baseline (57616.510 us; speedup 1.0000x reference)
//
#include <hip/hip_runtime.h>

// GRU  B=128, T=1024, IN=256, H=512, OUT=1  (all fp32)
//
// v3: persistent coop kernel, 256 wgs x 512 thr (8 waves/CU, 2/SIMD).
//   16 groups x 16 wgs (g = bid&15 -> all members on one XCD under round-robin).
//   Group owns 8 samples; wg owns 32 hidden j. Thread (j_loc in [0,32),
//   ks in [0,16)) holds W_hh[3][j][32ks..+32) + W_ih[3][j][16ks..+16)
//   = 144 floats, PINNED in VGPRs via opaque asm (compiler cannot sink the
//   loads back into the loop -- the round-2 failure mode, VGPR_Count=76).
//   x read directly from global (L1-broadcast, no LDS, no conflicts).
//   h exchanged via global double buffer + per-group monotonic atomic barrier
//   (agent scope, correct regardless of actual XCD placement).

#define B_    128
#define T_    1024
#define IN_   256
#define H_    512
#define NGRP  16
#define WPG   16
#define SGRP  8
#define JT    32
#define NT    512

__device__ __forceinline__ float sig_(float v){ return 1.0f/(1.0f + __expf(-v)); }
__device__ __forceinline__ float tanh_(float v){
  float e = __expf(2.0f*v);            // tanh = 1 - 2/(e^{2x}+1); inf-safe
  return 1.0f - 2.0f/(e + 1.0f);
}

#define FMA4(acc, v, warr, base) do{            \
  acc = fmaf((v).x, warr[(base)+0], acc);       \
  acc = fmaf((v).y, warr[(base)+1], acc);       \
  acc = fmaf((v).z, warr[(base)+2], acc);       \
  acc = fmaf((v).w, warr[(base)+3], acc); }while(0)

__global__ void __launch_bounds__(NT, 2)
rnn_persist(const float* __restrict__ x, const float* __restrict__ W_ih,
            const float* __restrict__ W_hh, const float* __restrict__ bias,
            const float* __restrict__ bias_n, float* __restrict__ h_buf,
            int* __restrict__ counters)
{
  const int bid   = (int)blockIdx.x;
  const int g     = bid & (NGRP-1);    // group; bid mod 16 fixes XCD (bid mod 8)
  const int w     = bid >> 4;          // wg within group [0,16)
  const int tid   = (int)threadIdx.x;
  const int j_loc = tid >> 4;          // [0,32)
  const int ks    = tid & 15;          // [0,16)
  const int jg    = w*JT + j_loc;      // global hidden index
  const int b0    = g*SGRP;            // first sample of group
  const int kh    = ks*32;             // W_hh k-chunk start (32 floats)
  const int kx    = ks*16;             // W_ih k-chunk start (16 floats)

  // ---- weights into registers ----
  float wr[32], wz[32], wn[32];
#pragma unroll
  for (int i=0;i<8;i++){
    const float4 a  = *(const float4*)&W_hh[(size_t)(      jg)*H_ + kh + 4*i];
    const float4 b4 = *(const float4*)&W_hh[(size_t)(H_  + jg)*H_ + kh + 4*i];
    const float4 c  = *(const float4*)&W_hh[(size_t)(2*H_+ jg)*H_ + kh + 4*i];
    wr[4*i+0]=a.x;  wr[4*i+1]=a.y;  wr[4*i+2]=a.z;  wr[4*i+3]=a.w;
    wz[4*i+0]=b4.x; wz[4*i+1]=b4.y; wz[4*i+2]=b4.z; wz[4*i+3]=b4.w;
    wn[4*i+0]=c.x;  wn[4*i+1]=c.y;  wn[4*i+2]=c.z;  wn[4*i+3]=c.w;
  }
  float wxr[16], wxz[16], wxn[16];
#pragma unroll
  for (int i=0;i<4;i++){
    const float4 a  = *(const float4*)&W_ih[(size_t)(      jg)*IN_ + kx + 4*i];
    const float4 b4 = *(const float4*)&W_ih[(size_t)(H_  + jg)*IN_ + kx + 4*i];
    const float4 c  = *(const float4*)&W_ih[(size_t)(2*H_+ jg)*IN_ + kx + 4*i];
    wxr[4*i+0]=a.x;  wxr[4*i+1]=a.y;  wxr[4*i+2]=a.z;  wxr[4*i+3]=a.w;
    wxz[4*i+0]=b4.x; wxz[4*i+1]=b4.y; wxz[4*i+2]=b4.z; wxz[4*i+3]=b4.w;
    wxn[4*i+0]=c.x;  wxn[4*i+1]=c.y;  wxn[4*i+2]=c.z;  wxn[4*i+3]=c.w;
  }
  float br  = bias[jg];
  float bz  = bias[H_ + jg];
  float bni = bias[2*H_ + jg];
  float bnh = bias_n[jg];

  // ---- PIN everything in VGPRs: opaque defs, loads cannot be sunk ----
#pragma unroll
  for (int i=0;i<32;i++){ asm volatile("" : "+v"(wr[i]), "+v"(wz[i]), "+v"(wn[i])); }
#pragma unroll
  for (int i=0;i<16;i++){ asm volatile("" : "+v"(wxr[i]), "+v"(wxz[i]), "+v"(wxn[i])); }
  asm volatile("" : "+v"(br), "+v"(bz), "+v"(bni), "+v"(bnh));

  float* const hb0 = h_buf;
  float* const hb1 = h_buf + (size_t)B_*H_;
  int dead = 0;

  for (int t=0; t<T_; ++t){
    const float* hc  = (t & 1) ? hb1 : hb0;
    float*       hnx = (t & 1) ? hb0 : hb1;

#pragma unroll 2
    for (int bb=0; bb<SGRP; ++bb){
      const float* hrow = hc + (size_t)(b0+bb)*H_ + kh;
      const float* xrow = x  + ((size_t)(b0+bb)*T_ + (size_t)t)*IN_ + kx;
      float accr=0.f, accz=0.f, accnh=0.f, accni=0.f;
      {
        const float4 h0 = *(const float4*)(hrow + 0);
        const float4 h1 = *(const float4*)(hrow + 4);
        const float4 h2 = *(const float4*)(hrow + 8);
        const float4 h3 = *(const float4*)(hrow + 12);
        FMA4(accr, h0, wr, 0);  FMA4(accr, h1, wr, 4);
        FMA4(accr, h2, wr, 8);  FMA4(accr, h3, wr, 12);
        FMA4(accz, h0, wz, 0);  FMA4(accz, h1, wz, 4);
        FMA4(accz, h2, wz, 8);  FMA4(accz, h3, wz, 12);
        FMA4(accnh,h0, wn, 0);  FMA4(accnh,h1, wn, 4);
        FMA4(accnh,h2, wn, 8);  FMA4(accnh,h3, wn, 12);
      }
      {
        const float4 h0 = *(const float4*)(hrow + 16);
        const float4 h1 = *(const float4*)(hrow + 20);
        const float4 h2 = *(const float4*)(hrow + 24);
        const float4 h3 = *(const float4*)(hrow + 28);
        FMA4(accr, h0, wr, 16); FMA4(accr, h1, wr, 20);
        FMA4(accr, h2, wr, 24); FMA4(accr, h3, wr, 28);
        FMA4(accz, h0, wz, 16); FMA4(accz, h1, wz, 20);
        FMA4(accz, h2, wz, 24); FMA4(accz, h3, wz, 28);
        FMA4(accnh,h0, wn, 16); FMA4(accnh,h1, wn, 20);
        FMA4(accnh,h2, wn, 24); FMA4(accnh,h3, wn, 28);
      }
      {
        const float4 x0 = *(const float4*)(xrow + 0);
        const float4 x1 = *(const float4*)(xrow + 4);
        const float4 x2 = *(const float4*)(xrow + 8);
        const float4 x3 = *(const float4*)(xrow + 12);
        FMA4(accr, x0, wxr, 0); FMA4(accr, x1, wxr, 4);
        FMA4(accr, x2, wxr, 8); FMA4(accr, x3, wxr, 12);
        FMA4(accz, x0, wxz, 0); FMA4(accz, x1, wxz, 4);
        FMA4(accz, x2, wxz, 8); FMA4(accz, x3, wxz, 12);
        FMA4(accni,x0, wxn, 0); FMA4(accni,x1, wxn, 4);
        FMA4(accni,x2, wxn, 8); FMA4(accni,x3, wxn, 12);
      }
      // reduce across the 16 ks-lanes (butterfly; result in all lanes)
#pragma unroll
      for (int m=1;m<16;m<<=1){
        accr  += __shfl_xor(accr,  m, 16);
        accz  += __shfl_xor(accz,  m, 16);
        accnh += __shfl_xor(accnh, m, 16);
        accni += __shfl_xor(accni, m, 16);
      }
      const float h_old = hc[(size_t)(b0+bb)*H_ + jg];
      const float r = sig_(accr + br);
      const float z = sig_(accz + bz);
      const float n = tanh_(accni + bni + r*(accnh + bnh));
      const float hnew = (1.0f - z)*n + z*h_old;
      if (ks == 0) hnx[(size_t)(b0+bb)*H_ + jg] = hnew;  // 16B/wave contiguous
    }
    __threadfence();       // release h stores to device scope
    __syncthreads();       // wg-wide completion before tid0 signals
    // per-group barrier: monotonic counter, no reset within a launch
    if (tid == 0 && !dead){
      __hip_atomic_fetch_add(&counters[g<<8], 1, __ATOMIC_RELEASE, __HIP_MEMORY_SCOPE_AGENT);
      const int target = WPG*(t+1);
      long long guard = 0;
      while (__hip_atomic_load(&counters[g<<8], __ATOMIC_ACQUIRE, __HIP_MEMORY_SCOPE_AGENT) < target){
        __builtin_amdgcn_s_sleep(2);
        if (++guard > (1LL<<18)) { dead = 1; break; }
      }
    }
    __syncthreads();
  }
}

__global__ void head_k(const float* __restrict__ h, const float* __restrict__ W_out,
                       const float* __restrict__ b_out, float* __restrict__ out)
{
  const int b = (int)threadIdx.x;
  if (b < B_){
    float acc = 0.f;
    for (int k=0;k<H_;k++) acc = fmaf(h[(size_t)b*H_ + k], W_out[k], acc);
    out[b] = sig_(acc + b_out[0]);
  }
}

extern "C" void kernel_launch(void* const* d_in, const int* in_sizes, int n_in,
                              void* d_out, int out_size, void* d_ws, size_t ws_size,
                              hipStream_t stream)
{
  const float* x    = (const float*)d_in[0];
  const float* Wih  = (const float*)d_in[1];
  const float* Whh  = (const float*)d_in[2];
  const float* bias = (const float*)d_in[3];
  const float* bn   = (const float*)d_in[4];
  const float* Wout = (const float*)d_in[5];
  const float* bout = (const float*)d_in[6];
  float* out   = (float*)d_out;
  float* h_buf = (float*)d_ws;                                        // 512 KB
  int* counters = (int*)((char*)d_ws + (size_t)2*B_*H_*sizeof(float)); // 16 x 1KB

  // zero h0 + barrier counters every launch (captured into the graph)
  hipMemsetAsync(d_ws, 0, (size_t)2*B_*H_*sizeof(float) + 32768, stream);

  void* args[7];
  args[0]=(void*)&x; args[1]=(void*)&Wih; args[2]=(void*)&Whh; args[3]=(void*)&bias;
  args[4]=(void*)&bn; args[5]=(void*)&h_buf; args[6]=(void*)&counters;
  hipError_t e = hipLaunchCooperativeKernel((const void*)rnn_persist,
                                            dim3(256), dim3(NT), args, 0, stream);
  if (e != hipSuccess){
    (void)hipGetLastError();
    rnn_persist<<<dim3(256), dim3(NT), 0, stream>>>(x, Wih, Whh, bias, bn, h_buf, counters);
  }
  // T_ even -> final h is in hb0
  head_k<<<dim3(1), dim3(128), 0, stream>>>(h_buf, Wout, bout, out);
}

// Round 4
// 21625.748 us; speedup vs baseline: 2.6643x; 2.6643x over previous
//
#include <hip/hip_runtime.h>
#include <stdint.h>

// GRU  B=128, T=1024, IN=256, H=512, OUT=1  (all fp32)
//
// v4: persistent kernel, 256 wgs x 512 thr (8 waves/CU, 2/SIMD), 1 wg/CU via LDS.
//   8 groups x 32 wgs (g = bid&7); group owns 16 samples; wg owns 16 hidden j.
//   Weights in LDS (150KB, bank-conflict-free padded rows), streamed to regs
//   per 4-sample tile. NO fences in the loop: h + flags exchanged through
//   IF-coherent sc0 sc1 loads/stores (inline asm); ordering via __syncthreads'
//   vmcnt drain before the flag store. RMW-free flag barrier (store-your-slot,
//   poll-all-32 in parallel). x-projection computed BEFORE the poll to hide
//   barrier latency. Thread (j_loc in [0,16), ks in [0,32)): k-chunks
//   h[16ks..+16), x[8ks..+8); butterfly reduce width-32; lanes ks<4 do gates.

#define B_    128
#define T_    1024
#define IN_   256
#define H_    512
#define NG    8
#define WPG   32
#define SGRP  16
#define JT    16
#define NT    512
#define PWH   520            // 520 % 32 == 8 -> b128 starts spread over all banks
#define PWX   260            // 260 % 32 == 4
#define LDS_BYTES ((48*PWH + 48*PWX)*4)   // 149,760 B

__device__ __forceinline__ float sig_(float v){ return 1.0f/(1.0f + __expf(-v)); }
__device__ __forceinline__ float tanh_(float v){
  float e = __expf(2.0f*v);              // tanh = 1 - 2/(e^{2x}+1); inf-safe
  return 1.0f - 2.0f/(e + 1.0f);
}

// IF-coherent (cache-bypassing) memory ops -- no L2 fences needed anywhere.
#define CLOAD4(dst, p)  asm volatile("global_load_dwordx4 %0, %1, off sc0 sc1" : "=v"(dst) : "v"(p) : "memory")
#define CLOAD1(dst, p)  asm volatile("global_load_dword %0, %1, off sc0 sc1"   : "=v"(dst) : "v"(p) : "memory")
#define CSTORE1(p, v)   asm volatile("global_store_dword %0, %1, off sc0 sc1"  :: "v"(p), "v"(v) : "memory")
#define VWAIT0()        do{ asm volatile("s_waitcnt vmcnt(0)" ::: "memory"); __builtin_amdgcn_sched_barrier(0); }while(0)

#define DOT4(a, u, v) do{ a=fmaf((u).x,(v).x,a); a=fmaf((u).y,(v).y,a); \
                          a=fmaf((u).z,(v).z,a); a=fmaf((u).w,(v).w,a);}while(0)

__global__ void __launch_bounds__(NT, 2)
rnn_persist(const float* __restrict__ x, const float* __restrict__ W_ih,
            const float* __restrict__ W_hh, const float* __restrict__ bias,
            const float* __restrict__ bias_n, float* __restrict__ h_buf,
            int* __restrict__ flags)
{
  extern __shared__ float lds[];
  float* WH = lds;              // [3*16][PWH]
  float* WX = lds + 48*PWH;     // [3*16][PWX]

  const int bid   = (int)blockIdx.x;
  const int g     = bid & (NG-1);
  const int w     = bid >> 3;
  const int tid   = (int)threadIdx.x;
  const int j_loc = tid >> 5;          // [0,16)
  const int ks    = tid & 31;          // [0,32)
  const int jg    = w*JT + j_loc;
  const int b0    = g*SGRP;
  const int kh    = ks*16;
  const int kx    = ks*8;
  const int lane  = tid & 63;

  // ---- stage weights into LDS (padded rows) ----
  for (int r = tid; r < 48*128; r += NT){
    const int gj = r >> 7, kb = (r & 127)*4;
    const int gate = gj >> 4, jj = gj & 15;
    const float4 v = *(const float4*)&W_hh[(size_t)(gate*H_ + w*JT + jj)*H_ + kb];
    *(float4*)&WH[gj*PWH + kb] = v;
  }
  for (int r = tid; r < 48*64; r += NT){
    const int gj = r >> 6, kb = (r & 63)*4;
    const int gate = gj >> 4, jj = gj & 15;
    const float4 v = *(const float4*)&W_ih[(size_t)(gate*H_ + w*JT + jj)*IN_ + kb];
    *(float4*)&WX[gj*PWX + kb] = v;
  }
  const float br  = bias[jg];
  const float bz  = bias[H_ + jg];
  const float bni = bias[2*H_ + jg];
  const float bnh = bias_n[jg];
  __syncthreads();

  float* const hb0 = h_buf;
  float* const hb1 = h_buf + (size_t)B_*H_;
  int dead = 0;

  for (int t=0; t<T_; ++t){
    const float* hc  = (t & 1) ? hb1 : hb0;
    float*       hnx = (t & 1) ? hb0 : hb1;

    float acc[4][4][4];   // [tile][ss][R, Z, NI, NH]

    // ---- x-phase (flag-independent; hides barrier latency) ----
#pragma unroll
    for (int tl=0; tl<4; ++tl){
      float4 xv[4][2];
#pragma unroll
      for (int ss=0; ss<4; ++ss){
        const float* xp = x + ((size_t)(b0 + tl*4 + ss)*T_ + (size_t)t)*IN_ + kx;
        xv[ss][0] = *(const float4*)xp;
        xv[ss][1] = *(const float4*)(xp+4);
        acc[tl][ss][0]=0.f; acc[tl][ss][1]=0.f; acc[tl][ss][2]=0.f; acc[tl][ss][3]=0.f;
      }
#pragma unroll
      for (int gte=0; gte<3; ++gte){
        const float4 wa = *(const float4*)&WX[(gte*16+j_loc)*PWX + kx];
        const float4 wb = *(const float4*)&WX[(gte*16+j_loc)*PWX + kx + 4];
        const int ai = (gte==2) ? 2 : gte;   // n-gate x-part -> NI
#pragma unroll
        for (int ss=0; ss<4; ++ss){
          DOT4(acc[tl][ss][ai], xv[ss][0], wa);
          DOT4(acc[tl][ss][ai], xv[ss][1], wb);
        }
      }
    }

    // ---- wait for h^t (RMW-free flag barrier; relaxed sc1 polls, no fences) ----
    if (t > 0 && !dead){
      const int* fp = &flags[g*WPG + (lane & 31)];
      int guard = 0;
      for (;;){
        int fv;
        CLOAD1(fv, fp);
        asm volatile("s_waitcnt vmcnt(0)" ::: "memory");
        if (__all(fv >= t)) break;
        if (++guard > (1<<16)) { dead = 1; break; }
      }
      __builtin_amdgcn_sched_barrier(0);
    }

    // ---- h-phase ----
#pragma unroll
    for (int tl=0; tl<4; ++tl){
      float4 hv[4][4]; float hold;
      const float* hop = hc + (size_t)(b0 + tl*4 + (ks&3))*H_ + jg;
      CLOAD1(hold, hop);
#pragma unroll
      for (int ss=0; ss<4; ++ss){
        const float* hp = hc + (size_t)(b0 + tl*4 + ss)*H_ + kh;
        CLOAD4(hv[ss][0], hp);
        CLOAD4(hv[ss][1], (hp+4));
        CLOAD4(hv[ss][2], (hp+8));
        CLOAD4(hv[ss][3], (hp+12));
      }
      VWAIT0();
#pragma unroll
      for (int gte=0; gte<3; ++gte){
        const float4 w0 = *(const float4*)&WH[(gte*16+j_loc)*PWH + kh];
        const float4 w1 = *(const float4*)&WH[(gte*16+j_loc)*PWH + kh + 4];
        const float4 w2 = *(const float4*)&WH[(gte*16+j_loc)*PWH + kh + 8];
        const float4 w3 = *(const float4*)&WH[(gte*16+j_loc)*PWH + kh + 12];
        const int ai = (gte==2) ? 3 : gte;   // n-gate h-part -> NH
#pragma unroll
        for (int ss=0; ss<4; ++ss){
          DOT4(acc[tl][ss][ai], hv[ss][0], w0);
          DOT4(acc[tl][ss][ai], hv[ss][1], w1);
          DOT4(acc[tl][ss][ai], hv[ss][2], w2);
          DOT4(acc[tl][ss][ai], hv[ss][3], w3);
        }
      }
      // butterfly reduce over the 32 ks-lanes (width-32, stays in-wave)
#pragma unroll
      for (int m=16; m>=1; m>>=1){
#pragma unroll
        for (int ss=0; ss<4; ++ss){
          acc[tl][ss][0] += __shfl_xor(acc[tl][ss][0], m, 32);
          acc[tl][ss][1] += __shfl_xor(acc[tl][ss][1], m, 32);
          acc[tl][ss][2] += __shfl_xor(acc[tl][ss][2], m, 32);
          acc[tl][ss][3] += __shfl_xor(acc[tl][ss][3], m, 32);
        }
      }
      if (ks < 4){
        const int s = ks;
        const float r = sig_(acc[tl][s][0] + br);
        const float z = sig_(acc[tl][s][1] + bz);
        const float n = tanh_(acc[tl][s][2] + bni + r*(acc[tl][s][3] + bnh));
        const float hnew = (1.0f - z)*n + z*hold;
        float* op = hnx + (size_t)(b0 + tl*4 + s)*H_ + jg;
        CSTORE1(op, hnew);
      }
    }

    // ---- signal: my h^{t+1} slice is globally visible ----
    __syncthreads();                 // drains vmcnt for ALL waves (release)
    if (tid == 0){
      int* fp = &flags[g*WPG + w];
      const int fv = t + 1;
      CSTORE1(fp, fv);
    }
  }
}

__global__ void head_k(const float* __restrict__ h, const float* __restrict__ W_out,
                       const float* __restrict__ b_out, float* __restrict__ out)
{
  const int b = (int)threadIdx.x;
  if (b < B_){
    float acc = 0.f;
    for (int k=0;k<H_;k++) acc = fmaf(h[(size_t)b*H_ + k], W_out[k], acc);
    out[b] = sig_(acc + b_out[0]);
  }
}

extern "C" void kernel_launch(void* const* d_in, const int* in_sizes, int n_in,
                              void* d_out, int out_size, void* d_ws, size_t ws_size,
                              hipStream_t stream)
{
  const float* x    = (const float*)d_in[0];
  const float* Wih  = (const float*)d_in[1];
  const float* Whh  = (const float*)d_in[2];
  const float* bias = (const float*)d_in[3];
  const float* bn   = (const float*)d_in[4];
  const float* Wout = (const float*)d_in[5];
  const float* bout = (const float*)d_in[6];
  float* out   = (float*)d_out;
  float* h_buf = (float*)d_ws;                                         // 512 KB
  int* flags   = (int*)((char*)d_ws + (size_t)2*B_*H_*sizeof(float));  // 1 KB

  // zero h0 + flags every launch (captured into the graph)
  hipMemsetAsync(d_ws, 0, (size_t)2*B_*H_*sizeof(float) + 4096, stream);

  (void)hipFuncSetAttribute((const void*)rnn_persist,
                            hipFuncAttributeMaxDynamicSharedMemorySize, LDS_BYTES);

  void* args[7];
  args[0]=(void*)&x; args[1]=(void*)&Wih; args[2]=(void*)&Whh; args[3]=(void*)&bias;
  args[4]=(void*)&bn; args[5]=(void*)&h_buf; args[6]=(void*)&flags;
  hipError_t e = hipLaunchCooperativeKernel((const void*)rnn_persist,
                                            dim3(256), dim3(NT), args, LDS_BYTES, stream);
  if (e != hipSuccess){
    (void)hipGetLastError();
    rnn_persist<<<dim3(256), dim3(NT), LDS_BYTES, stream>>>(x, Wih, Whh, bias, bn, h_buf, flags);
  }
  // T_ even -> final h in hb0
  head_k<<<dim3(1), dim3(128), 0, stream>>>(h_buf, Wout, bout, out);
}

// Round 6
// 14592.961 us; speedup vs baseline: 3.9482x; 1.4819x over previous
//
#include <hip/hip_runtime.h>
#include <stdint.h>

// GRU  B=128, T=1024, IN=256, H=512, OUT=1  (all fp32)
//
// v6 = v5's call-1-validated compute + hardened sync (v5 failed only the
// post-timing revalidation => replay nondeterminism via the poll-guard
// bailout, not a math bug).
//   256 wgs x 512 thr persistent kernel (8 waves/CU, 2/SIMD).
//   8 groups x 32 wgs (g=bid&7); group owns 16 samples; wg owns 16 hidden j.
//   Weights register-resident, asm-pinned (148 f/thread).
//   h staged once per wg per step into chunk-padded LDS (16f chunks -> 20f).
//   DPP row_shr rowsum over the 16 ks-lanes (VALU pipe).
//   Cross-wg sync: RMW-free monotonic flags via sc0/sc1 ops (v4-proven), with
//   s_sleep backoff + 1<<21 guard (~0.3s) so spurious bailouts are impossible.
//   Head = separate kernel (kernel-boundary coherence).

#define B_    128
#define T_    1024
#define IN_   256
#define H_    512
#define NG    8
#define WPG   32
#define SGRP  16
#define JT    16
#define NT    512
#define RW    640                 // 32 chunks x 20 floats (padded)
#define LDS_DYN (SGRP*RW*4)       // 40,960 B h tile

__device__ __forceinline__ float sig_(float v){ return 1.0f/(1.0f + __expf(-v)); }
__device__ __forceinline__ float tanh_(float v){
  float e = __expf(2.0f*v);       // tanh = 1 - 2/(e^{2x}+1); inf-safe
  return 1.0f - 2.0f/(e + 1.0f);
}

// IF-coherent (cache-bypassing) ops -- no L2 fences needed anywhere.
#define CLOAD4(dst, p)  asm volatile("global_load_dwordx4 %0, %1, off sc0 sc1" : "=v"(dst) : "v"(p) : "memory")
#define CLOAD1(dst, p)  asm volatile("global_load_dword %0, %1, off sc0 sc1"   : "=v"(dst) : "v"(p) : "memory")
#define CSTORE1(p, v)   asm volatile("global_store_dword %0, %1, off sc0 sc1"  :: "v"(p), "v"(v) : "memory")
#define VWAIT0()        do{ asm volatile("s_waitcnt vmcnt(0)" ::: "memory"); __builtin_amdgcn_sched_barrier(0); }while(0)

#define FMA4A(acc, v, warr, base) do{           \
  acc = fmaf((v).x, warr[(base)+0], acc);       \
  acc = fmaf((v).y, warr[(base)+1], acc);       \
  acc = fmaf((v).z, warr[(base)+2], acc);       \
  acc = fmaf((v).w, warr[(base)+3], acc); }while(0)

// sum over each 16-lane row; full sum lands in lane 15 of the row (VALU DPP).
__device__ __forceinline__ float rowsum16(float v){
  float s = v; int t_;
  t_ = __builtin_amdgcn_update_dpp(0, __float_as_int(s), 0x111, 0xF, 0xF, true); s += __int_as_float(t_);
  t_ = __builtin_amdgcn_update_dpp(0, __float_as_int(s), 0x112, 0xF, 0xF, true); s += __int_as_float(t_);
  t_ = __builtin_amdgcn_update_dpp(0, __float_as_int(s), 0x114, 0xF, 0xF, true); s += __int_as_float(t_);
  t_ = __builtin_amdgcn_update_dpp(0, __float_as_int(s), 0x118, 0xF, 0xF, true); s += __int_as_float(t_);
  return s;
}

// poll all 32 group flags >= target. s_sleep backoff => low fabric pressure;
// guard 1<<21 (~0.3s) => spurious trips impossible.
__device__ __forceinline__ int poll_group(const int* fbase, int lane, int target){
  const int* fp = fbase + (lane & 31);
  int guard = 0;
  for (;;){
    int fv;
    CLOAD1(fv, fp);
    asm volatile("s_waitcnt vmcnt(0)" ::: "memory");
    if (__all(fv >= target)) return 0;
    __builtin_amdgcn_s_sleep(4);
    if (++guard > (1<<21)) return 1;
  }
}

// stage 16x512 h tile into chunk-padded LDS (thread = (ss, chunk))
__device__ __forceinline__ void stage_h(const float* hc, float* HT, int tid, int b0){
  const int ss = tid >> 5, c = tid & 31;
  const float* src = hc + (size_t)(b0+ss)*H_ + c*16;
  float4 v0,v1,v2,v3;
  CLOAD4(v0, src); CLOAD4(v1, (src+4)); CLOAD4(v2, (src+8)); CLOAD4(v3, (src+12));
  VWAIT0();
  float* d = HT + ss*RW + c*20;
  *(float4*)(d)    = v0; *(float4*)(d+4)  = v1;
  *(float4*)(d+8)  = v2; *(float4*)(d+12) = v3;
}

__global__ void __launch_bounds__(NT, 2)
rnn_persist(const float* __restrict__ x, const float* __restrict__ W_ih,
            const float* __restrict__ W_hh, const float* __restrict__ bias,
            const float* __restrict__ bias_n, float* __restrict__ h_buf,
            int* __restrict__ flags)
{
  extern __shared__ float HT[];        // [16][RW]

  const int bid = (int)blockIdx.x;
  const int g   = bid & (NG-1);
  const int w   = bid >> 3;
  const int tid = (int)threadIdx.x;
  const int j   = tid >> 5;            // [0,16)
  const int sg  = (tid >> 4) & 1;      // sample half
  const int ks  = tid & 15;            // k-group [0,16)
  const int jg  = w*JT + j;
  const int b0  = g*SGRP;
  const int lane = tid & 63;

  // ---- weights into registers (k-chunks ks and ks+16 for W_hh) ----
  float wr[32], wz[32], wn[32];
#pragma unroll
  for (int q=0;q<4;q++){
    *(float4*)&wr[4*q]    = *(const float4*)&W_hh[((size_t)0*H_ + jg)*H_ + ks*16 + 4*q];
    *(float4*)&wr[16+4*q] = *(const float4*)&W_hh[((size_t)0*H_ + jg)*H_ + (ks+16)*16 + 4*q];
    *(float4*)&wz[4*q]    = *(const float4*)&W_hh[((size_t)1*H_ + jg)*H_ + ks*16 + 4*q];
    *(float4*)&wz[16+4*q] = *(const float4*)&W_hh[((size_t)1*H_ + jg)*H_ + (ks+16)*16 + 4*q];
    *(float4*)&wn[4*q]    = *(const float4*)&W_hh[((size_t)2*H_ + jg)*H_ + ks*16 + 4*q];
    *(float4*)&wn[16+4*q] = *(const float4*)&W_hh[((size_t)2*H_ + jg)*H_ + (ks+16)*16 + 4*q];
  }
  float wxr[16], wxz[16], wxn[16];
#pragma unroll
  for (int q=0;q<4;q++){
    *(float4*)&wxr[4*q] = *(const float4*)&W_ih[((size_t)0*H_ + jg)*IN_ + ks*16 + 4*q];
    *(float4*)&wxz[4*q] = *(const float4*)&W_ih[((size_t)1*H_ + jg)*IN_ + ks*16 + 4*q];
    *(float4*)&wxn[4*q] = *(const float4*)&W_ih[((size_t)2*H_ + jg)*IN_ + ks*16 + 4*q];
  }
  float br = bias[jg], bz = bias[H_+jg], bni = bias[2*H_+jg], bnh = bias_n[jg];
  // pin: loads cannot be sunk back into the loop (round-2 failure mode)
#pragma unroll
  for (int i=0;i<32;i++) asm volatile("" : "+v"(wr[i]), "+v"(wz[i]), "+v"(wn[i]));
#pragma unroll
  for (int i=0;i<16;i++) asm volatile("" : "+v"(wxr[i]), "+v"(wxz[i]), "+v"(wxn[i]));
  asm volatile("" : "+v"(br), "+v"(bz), "+v"(bni), "+v"(bnh));

  float* const hb0 = h_buf;
  float* const hb1 = h_buf + (size_t)B_*H_;
  int dead = 0;

  for (int t=0; t<T_; ++t){
    const float* hc  = (t & 1) ? hb1 : hb0;
    float*       hnx = (t & 1) ? hb0 : hb1;

    // ---- x-phase (flag-independent; hides producer lag + HBM latency) ----
    float acc[8][4];   // [m][R,Z,NI,NH]
#pragma unroll
    for (int m=0;m<8;m++){
      const int ss = sg*8 + m;
      const float* xr = x + ((size_t)(b0+ss)*T_ + (size_t)t)*IN_ + ks*16;
      const float4 x0 = *(const float4*)(xr);
      const float4 x1 = *(const float4*)(xr+4);
      const float4 x2 = *(const float4*)(xr+8);
      const float4 x3 = *(const float4*)(xr+12);
      float aR=0.f, aZ=0.f, aNI=0.f;
      FMA4A(aR, x0, wxr, 0); FMA4A(aR, x1, wxr, 4); FMA4A(aR, x2, wxr, 8); FMA4A(aR, x3, wxr, 12);
      FMA4A(aZ, x0, wxz, 0); FMA4A(aZ, x1, wxz, 4); FMA4A(aZ, x2, wxz, 8); FMA4A(aZ, x3, wxz, 12);
      FMA4A(aNI,x0, wxn, 0); FMA4A(aNI,x1, wxn, 4); FMA4A(aNI,x2, wxn, 8); FMA4A(aNI,x3, wxn, 12);
      acc[m][0]=aR; acc[m][1]=aZ; acc[m][2]=aNI; acc[m][3]=0.f;
    }

    // ---- wait for h^t, then stage it into LDS ----
    if (t > 0 && !dead) dead = poll_group(flags + g*WPG, lane, t);
    stage_h(hc, HT, tid, b0);
    __syncthreads();

    // ---- h-phase: per sample, read padded LDS chunks, FMA vs reg weights ----
#pragma unroll
    for (int m=0;m<8;m++){
      const int ss = sg*8 + m;
      const float* hrow = HT + ss*RW;
      float aR = acc[m][0], aZ = acc[m][1], aNH = acc[m][3];
      {
        const float* p = hrow + ks*20;
        const float4 a0 = *(const float4*)(p);
        const float4 a1 = *(const float4*)(p+4);
        const float4 a2 = *(const float4*)(p+8);
        const float4 a3 = *(const float4*)(p+12);
        FMA4A(aR, a0, wr, 0);  FMA4A(aR, a1, wr, 4);  FMA4A(aR, a2, wr, 8);  FMA4A(aR, a3, wr, 12);
        FMA4A(aZ, a0, wz, 0);  FMA4A(aZ, a1, wz, 4);  FMA4A(aZ, a2, wz, 8);  FMA4A(aZ, a3, wz, 12);
        FMA4A(aNH,a0, wn, 0);  FMA4A(aNH,a1, wn, 4);  FMA4A(aNH,a2, wn, 8);  FMA4A(aNH,a3, wn, 12);
      }
      {
        const float* p = hrow + (ks+16)*20;
        const float4 a0 = *(const float4*)(p);
        const float4 a1 = *(const float4*)(p+4);
        const float4 a2 = *(const float4*)(p+8);
        const float4 a3 = *(const float4*)(p+12);
        FMA4A(aR, a0, wr, 16); FMA4A(aR, a1, wr, 20); FMA4A(aR, a2, wr, 24); FMA4A(aR, a3, wr, 28);
        FMA4A(aZ, a0, wz, 16); FMA4A(aZ, a1, wz, 20); FMA4A(aZ, a2, wz, 24); FMA4A(aZ, a3, wz, 28);
        FMA4A(aNH,a0, wn, 16); FMA4A(aNH,a1, wn, 20); FMA4A(aNH,a2, wn, 24); FMA4A(aNH,a3, wn, 28);
      }
      acc[m][0]=aR; acc[m][1]=aZ; acc[m][3]=aNH;
    }

    // ---- reduce over 16 ks-lanes (DPP, VALU pipe; sum lands at ks==15) ----
#pragma unroll
    for (int m=0;m<8;m++){
      acc[m][0] = rowsum16(acc[m][0]);
      acc[m][1] = rowsum16(acc[m][1]);
      acc[m][2] = rowsum16(acc[m][2]);
      acc[m][3] = rowsum16(acc[m][3]);
    }

    // ---- gates + h store (lane ks==15 of each row owns (j, 8 samples)) ----
    if (ks == 15){
#pragma unroll
      for (int m=0;m<8;m++){
        const int ss = sg*8 + m;
        const float h_old = HT[ss*RW + w*20 + j];   // chunk w = h idx [16w,16w+16)
        const float r = sig_(acc[m][0] + br);
        const float z = sig_(acc[m][1] + bz);
        const float n = tanh_(acc[m][2] + bni + r*(acc[m][3] + bnh));
        const float hnew = (1.0f - z)*n + z*h_old;
        float* op = hnx + (size_t)(b0+ss)*H_ + jg;
        CSTORE1(op, hnew);
      }
    }
    // wave-wide unconditional drain of this wave's h stores (release side)
    asm volatile("s_waitcnt vmcnt(0)" ::: "memory");
    __syncthreads();                  // all waves of the wg drained
    if (tid == 0){
      int* fp = &flags[g*WPG + w];
      const int fv = t + 1;
      CSTORE1(fp, fv);
    }
  }
}

__global__ void head_k(const float* __restrict__ h, const float* __restrict__ W_out,
                       const float* __restrict__ b_out, float* __restrict__ out)
{
  const int b = (int)blockIdx.x;       // 128 blocks, one sample each
  const int l = (int)threadIdx.x;      // 64 lanes
  const float* hp = h + (size_t)b*H_ + l*8;
  const float* wp = W_out + l*8;
  float a = 0.f;
#pragma unroll
  for (int q=0;q<2;q++){
    const float4 hv = *(const float4*)(hp + 4*q);
    const float4 wv = *(const float4*)(wp + 4*q);
    a = fmaf(hv.x, wv.x, a); a = fmaf(hv.y, wv.y, a);
    a = fmaf(hv.z, wv.z, a); a = fmaf(hv.w, wv.w, a);
  }
#pragma unroll
  for (int m=1;m<64;m<<=1) a += __shfl_xor(a, m, 64);
  if (l == 0) out[b] = sig_(a + b_out[0]);
}

extern "C" void kernel_launch(void* const* d_in, const int* in_sizes, int n_in,
                              void* d_out, int out_size, void* d_ws, size_t ws_size,
                              hipStream_t stream)
{
  const float* x    = (const float*)d_in[0];
  const float* Wih  = (const float*)d_in[1];
  const float* Whh  = (const float*)d_in[2];
  const float* bias = (const float*)d_in[3];
  const float* bn   = (const float*)d_in[4];
  const float* Wout = (const float*)d_in[5];
  const float* bout = (const float*)d_in[6];
  float* out   = (float*)d_out;
  float* h_buf = (float*)d_ws;                                         // 512 KB
  int* flags   = (int*)((char*)d_ws + (size_t)2*B_*H_*sizeof(float));  // 1 KB used

  // zero h0 + flags every launch (captured into the graph)
  hipMemsetAsync(d_ws, 0, (size_t)2*B_*H_*sizeof(float) + 4096, stream);

  (void)hipFuncSetAttribute((const void*)rnn_persist,
                            hipFuncAttributeMaxDynamicSharedMemorySize, LDS_DYN);

  void* args[7];
  args[0]=(void*)&x;    args[1]=(void*)&Wih;  args[2]=(void*)&Whh; args[3]=(void*)&bias;
  args[4]=(void*)&bn;   args[5]=(void*)&h_buf; args[6]=(void*)&flags;
  hipError_t e = hipLaunchCooperativeKernel((const void*)rnn_persist,
                                            dim3(256), dim3(NT), args, LDS_DYN, stream);
  if (e != hipSuccess){
    (void)hipGetLastError();
    rnn_persist<<<dim3(256), dim3(NT), LDS_DYN, stream>>>(x, Wih, Whh, bias, bn, h_buf, flags);
  }
  // T_ even -> final h in hb0; kernel boundary makes h_buf coherent for head_k
  head_k<<<dim3(128), dim3(64), 0, stream>>>(h_buf, Wout, bout, out);
}